// Round 7
// baseline (2736.789 us; speedup 1.0000x reference)
//
#include <hip/hip_runtime.h>
#include <hip/hip_bf16.h>
#include <math.h>

#define BB 64      // batch
#define TT 512     // encoder time
#define NS 128     // decode steps
#define SD 512     // lstm hidden
#define ATT 128
#define NC 64      // num classes
#define KX 1024    // X row: 512 ctx/h1 + 512 rec

typedef __attribute__((ext_vector_type(8))) short bf8;   // 8 bf16 (4 VGPRs)
typedef __attribute__((ext_vector_type(4))) float f4;

__device__ __forceinline__ float sigm(float x) { return 1.0f / (1.0f + expf(-x)); }
__device__ __forceinline__ float b2f(short s) {
    union { unsigned u; float f; } c; c.u = ((unsigned)(unsigned short)s) << 16; return c.f;
}
__device__ __forceinline__ unsigned bfbits(float x) {
    __hip_bfloat16 h(x); unsigned short s; __builtin_memcpy(&s, &h, 2); return (unsigned)s;
}
#define MFMA16(a, b, c) __builtin_amdgcn_mfma_f32_16x16x32_bf16((a), (b), (c), 0, 0, 0)

// ---- L3-point communication ----
// WRITES: device atomics (atomicExch) — execute at the device coherence point
// (L3) and leave the line RESIDENT there (unlike sc0 sc1 write-through, which
// is non-allocating and lands in DRAM: ~1-2us acks + DRAM-latency polls).
// READS of flag lines: sc0 sc1 loads (bypass L1/L2, hit L3-resident line).
// READS of X data: NORMAL cached loads — per-step-fresh addresses guarantee
// no stale L1/L2 copy can exist; the L2 miss pulls the L3-resident line.
__device__ __forceinline__ unsigned ld_u32_sc(const unsigned* p) {
    unsigned v;
    asm volatile("global_load_dword %0, %1, off sc0 sc1\ns_waitcnt vmcnt(0)"
                 : "=v"(v) : "v"(p) : "memory");
    return v;
}

// Producer: per-thread vmcnt drain (data atomics ack'd at L3), block sync,
// thread 0 posts the block's monotonic step ticket via atomic (L3-resident).
__device__ __forceinline__ void post_flag(unsigned* flag, unsigned tk)
{
    asm volatile("s_waitcnt vmcnt(0)" ::: "memory");
    __syncthreads();
    if (threadIdx.x == 0) atomicExch(flag, tk);
}
// Consumer: threads 0..n-1 each poll ONE producer line until >= tk.
__device__ __forceinline__ void wait_flags(const unsigned* f, int n, unsigned tk)
{
    if ((int)threadIdx.x < n) {
        while (ld_u32_sc(f + threadIdx.x * 32) < tk)
            __builtin_amdgcn_s_sleep(1);
    }
    __syncthreads();
}

// 16-chunk MFMA GEMM over one X row; NORMAL cached loads (per-step-fresh
// addresses guarantee coherence); W fragments from registers.
template<int BASE>
__device__ __forceinline__ f4 gemm16r(const __hip_bfloat16* Xrow, int quad,
                                      const bf8 (&wreg)[32], f4 acc)
{
    const bf8* Bq = (const bf8*)Xrow + quad;
    bf8 r[16];
#pragma unroll
    for (int i = 0; i < 16; ++i) r[i] = Bq[(BASE + i) * 4];
#pragma unroll
    for (int i = 0; i < 16; ++i) acc = MFMA16(wreg[BASE + i], r[i], acc);
    return acc;
}

// ---------------- fp32 -> bf16 convert (vec4) ----------------
__global__ void f2b_kernel(const float* __restrict__ src, __hip_bfloat16* __restrict__ dst, int n)
{
    int i = (blockIdx.x * blockDim.x + threadIdx.x) * 4;
    if (i < n) {
        float4 v = *(const float4*)(src + i);
        dst[i]     = __hip_bfloat16(v.x);
        dst[i + 1] = __hip_bfloat16(v.y);
        dst[i + 2] = __hip_bfloat16(v.z);
        dst[i + 3] = __hip_bfloat16(v.w);
    }
}

// ---------------- transpose h: [b][t][d] f32 -> hT [b][d][t] bf16 ----------------
__global__ __launch_bounds__(256) void transpose_h_kernel(const float* __restrict__ h,
                                                          __hip_bfloat16* __restrict__ hT)
{
    int bidx = blockIdx.x;
    int b = bidx >> 6, tt0 = ((bidx >> 3) & 7) * 64, dd0 = (bidx & 7) * 64;
    __shared__ __hip_bfloat16 tile[64][65];
    int dd = threadIdx.x & 63, r4 = threadIdx.x >> 6;
#pragma unroll
    for (int i = 0; i < 64; i += 4) {
        int tl = i + r4;
        tile[tl][dd] = __hip_bfloat16(h[((size_t)b * TT + tt0 + tl) * SD + dd0 + dd]);
    }
    __syncthreads();
#pragma unroll
    for (int i = 0; i < 64; i += 4) {
        int dl = i + r4;
        hT[((size_t)b * SD + dd0 + dl) * TT + tt0 + dd] = tile[dd][dl];
    }
}

// ---------------- LSTM0 weights [2048][1024]: ctx cols | rec cols ----------------
__global__ void prep_w1_kernel(const float* __restrict__ Wih, const float* __restrict__ Whh,
                               __hip_bfloat16* __restrict__ W)
{
    int idx = blockIdx.x * blockDim.x + threadIdx.x;   // 2048*1024
    if (idx >= 2048 * KX) return;
    int np = idx >> 10, kk = idx & 1023;
    int q = np & 3, d = np >> 2, j = q * 512 + d;
    float v = (kk < 512) ? Wih[j * 576 + 64 + kk] : Whh[j * 512 + kk - 512];
    W[idx] = __hip_bfloat16(v);
}

// ---------------- LSTM1 weights [2048][1024] ----------------
__global__ void prep_w2_kernel(const float* __restrict__ Wih, const float* __restrict__ Whh,
                               __hip_bfloat16* __restrict__ W)
{
    int idx = blockIdx.x * blockDim.x + threadIdx.x;
    if (idx >= 2048 * KX) return;
    int np = idx >> 10, kk = idx & 1023;
    int q = np & 3, d = np >> 2, j = q * 512 + d;
    float v = (kk < 512) ? Wih[j * 512 + kk] : Whh[j * 512 + kk - 512];
    W[idx] = __hip_bfloat16(v);
}

// ---------------- biases (gate-interleaved f4) + per-token Wih0 column gather ----------------
__global__ void prep_misc_kernel(const float* __restrict__ Wih0,
                                 const float* __restrict__ bih0, const float* __restrict__ bhh0,
                                 const float* __restrict__ bih1, const float* __restrict__ bhh1,
                                 float* __restrict__ b1v, float* __restrict__ b2v,
                                 float* __restrict__ woh)   // [64 tok][512 d] f4
{
    int idx = blockIdx.x * blockDim.x + threadIdx.x;   // 64*512
    if (idx >= 64 * 512) return;
    int tok = idx >> 9, d = idx & 511;
    float4 w;
    w.x = Wih0[(0 * 512 + d) * 576 + tok];
    w.y = Wih0[(1 * 512 + d) * 576 + tok];
    w.z = Wih0[(2 * 512 + d) * 576 + tok];
    w.w = Wih0[(3 * 512 + d) * 576 + tok];
    ((float4*)woh)[idx] = w;
    if (tok == 0) {
        float4 b1, b2;
        b1.x = bih0[d] + bhh0[d];             b1.y = bih0[512 + d] + bhh0[512 + d];
        b1.z = bih0[1024 + d] + bhh0[1024 + d]; b1.w = bih0[1536 + d] + bhh0[1536 + d];
        b2.x = bih1[d] + bhh1[d];             b2.y = bih1[512 + d] + bhh1[512 + d];
        b2.z = bih1[1024 + d] + bhh1[1024 + d]; b2.w = bih1[1536 + d] + bhh1[1536 + d];
        ((float4*)b1v)[d] = b1;
        ((float4*)b2v)[d] = b2;
    }
}

// ---------------- init: step-0 X buffers, c states, flags ----------------
__global__ void init_kernel(const float* __restrict__ h,
                            __hip_bfloat16* __restrict__ X1_0,
                            __hip_bfloat16* __restrict__ X2_0,
                            float* __restrict__ c1, float* __restrict__ c2,
                            unsigned* __restrict__ bar)
{
    int idx = blockIdx.x * blockDim.x + threadIdx.x;   // 64*1024
    if (idx >= 64 * KX) return;
    int b = idx >> 10, col = idx & 1023;
    __hip_bfloat16 z(0.0f);
    X1_0[idx] = (col < 512) ? __hip_bfloat16(h[(size_t)b * TT * SD + col]) : z;  // ctx0 | h1(-1)=0
    X2_0[idx] = z;                                                               // h2(-1)=0
    if (idx < 512 * 64) { c1[idx] = 0.f; c2[idx] = 0.f; }
    if (idx < 16384) bar[idx] = 0u;
}

// ---------------- persistent decode kernel ----------------
// 256 blocks x 512 threads, 1 block/CU. Blocks 0..127 ("A"): LSTM0 rows;
// 128..255 ("B"): LSTM1 rows. W tiles in registers, cell state in registers,
// hT slice (ab,dch) 128 KB LDS-resident (swizzled). Per-step X buffers =>
// cached X reads. Dataflow: fC(t-1) -> A -> fA -> B -> fB -> attention -> fC.
// All cross-block writes (h1/h2/ctx/flags) are DEVICE ATOMICS => L3-resident.
__global__ __launch_bounds__(512, 1) void decode_kernel(
    const __hip_bfloat16* __restrict__ W1, const __hip_bfloat16* __restrict__ W2,
    const __hip_bfloat16* __restrict__ Wphib, const float* __restrict__ bphi,
    const __hip_bfloat16* __restrict__ psib, const __hip_bfloat16* __restrict__ hT,
    __hip_bfloat16* X1base, __hip_bfloat16* X2base,
    __hip_bfloat16* scb, const int* __restrict__ xtok,
    const float* __restrict__ b1v, const float* __restrict__ b2v,
    const float* __restrict__ woh, unsigned* __restrict__ bar)
{
    __shared__ bf8 hTl[128 * 64];                        // 128 KB swizzled hT slice
    __shared__ float h2s[512], phis[128], es[512], red[512], wred[16];

    const int bid = blockIdx.x, tid = threadIdx.x;
    const int lane = tid & 63, w = tid >> 6;
    const int mr = lane & 15, quad = lane >> 4;
    const bool isA = bid < 128;
    // attention role: co-locate the 4 dch blocks of one ab on one XCD (bid%8)
    const int ab = (bid & 7) * 8 + ((bid >> 3) & 7), dch = bid >> 6;

    unsigned* fA = bar;                  // 128 x 32 words (128B lines)
    unsigned* fB = bar + 128 * 32;       // 128 x 32
    unsigned* fC = bar + 256 * 32;       // 256 x 32

    // ---- prologue: W rows -> registers (LSTM waves only) ----
    bf8 wreg[32];
    if (tid < 256) {
        const __hip_bfloat16* Wg = isA ? W1 : W2;
        const int m0 = (bid & 127) * 16;
        const bf8* src = (const bf8*)(Wg + (size_t)(m0 + mr) * KX) + quad;
#pragma unroll
        for (int ko = 0; ko < 32; ++ko) wreg[ko] = src[ko * 4];
    }
    // ---- prologue: hT slice -> LDS (swizzled) ----
    {
        const bf8* src = (const bf8*)hT + ((size_t)ab * SD + dch * 128) * 64;
        for (int it = 0; it < 16; ++it) {
            int gidx = it * 512 + tid;                   // 0..8191
            int d = gidx >> 6, g = gidx & 63;
            hTl[d * 64 + (g ^ (d & 7))] = src[gidx];
        }
    }
    __syncthreads();

    const int dl = (bid & 127) * 4 + quad;   // this thread's hidden index d
    const int bb = w * 16 + mr;              // this thread's batch (tid<256)
    const f4 biasv = isA ? ((const f4*)b1v)[dl & 511] : ((const f4*)b2v)[dl & 511];
    const int* xrow = xtok + (bb & 63) * NS;

    float cr = 0.f;                          // persistent cell state
    f4 accP = {0, 0, 0, 0};                  // A: recurrent partial; h1(-1)=0 => 0

    for (int t = 0; t < NS; ++t) {
        __hip_bfloat16* X1c = X1base + (size_t)t * BB * KX;
        __hip_bfloat16* X1n = X1c + (size_t)BB * KX;
        __hip_bfloat16* X2c = X2base + (size_t)t * BB * KX;
        __hip_bfloat16* X2n = X2c + (size_t)BB * KX;

        if (isA) {
            // issue token-column gather early (independent of ctx)
            f4 wo = {0, 0, 0, 0};
            if (tid < 256) wo = ((const f4*)woh)[(size_t)xrow[t] * 512 + dl];
            // wait ctx(t-1) from all 256 attention blocks (t=0: trivially 0)
            wait_flags(fC, 256, (unsigned)t);
            if (tid < 256) {
                f4 acc = gemm16r<0>(X1c + (size_t)bb * KX, quad, wreg, accP);
                acc.x += biasv.x + wo.x; acc.y += biasv.y + wo.y;
                acc.z += biasv.z + wo.z; acc.w += biasv.w + wo.w;
                float cn = sigm(acc.y) * cr + sigm(acc.x) * tanhf(acc.z);
                float hn = sigm(acc.w) * tanhf(cn);
                cr = cn;
                // packed-pair atomic publish (L3-resident): lanes quad/quad^1
                float hp = __shfl_xor(hn, 16);
                if (!(quad & 1)) {
                    unsigned pk = bfbits(hn) | (bfbits(hp) << 16);
                    atomicExch((unsigned*)(X2c + (size_t)bb * KX + dl), pk);       // h1 -> LSTM1 in
                    atomicExch((unsigned*)(X1n + (size_t)bb * KX + 512 + dl), pk); // h1 -> next rec
                }
            }
            post_flag(fA + bid * 32, (unsigned)(t + 1));
            // recurrent prefetch for t+1 (needs ALL A's h1)
            wait_flags(fA, 128, (unsigned)(t + 1));
            if (tid < 256) {
                f4 z = {0, 0, 0, 0};
                accP = gemm16r<16>(X1n + (size_t)bb * KX, quad, wreg, z);
            }
        } else {
            // recurrent prefetch over h2(t-1): ordered by own attn(t-1) wait on fB
            f4 pre = {0, 0, 0, 0};
            if (tid < 256) {
                f4 z = {0, 0, 0, 0};
                pre = gemm16r<16>(X2c + (size_t)bb * KX, quad, wreg, z);
            }
            // finish needs h1(t) from all A blocks
            wait_flags(fA, 128, (unsigned)(t + 1));
            float hnv = 0.f;
            if (tid < 256) {
                f4 acc = gemm16r<0>(X2c + (size_t)bb * KX, quad, wreg, pre);
                acc.x += biasv.x; acc.y += biasv.y; acc.z += biasv.z; acc.w += biasv.w;
                float cn = sigm(acc.y) * cr + sigm(acc.x) * tanhf(acc.z);
                hnv = sigm(acc.w) * tanhf(cn);
                cr = cn;
                float hp2 = __shfl_xor(hnv, 16);
                if (!(quad & 1)) {
                    unsigned pk = bfbits(hnv) | (bfbits(hp2) << 16);
                    atomicExch((unsigned*)(X2n + (size_t)bb * KX + 512 + dl), pk); // h2 rec
                }
            }
            post_flag(fB + (bid & 127) * 32, (unsigned)(t + 1));
            if (tid < 256)                                       // off critical path
                scb[((size_t)bb * NS + t) * 1024 + dl] = __hip_bfloat16(hnv);
        }

        // ---- attention (all 256 blocks as (ab, dch)); needs all h2(t) ----
        wait_flags(fB, 128, (unsigned)(t + 1));
        {
            if (tid < 64) {                 // h2(t): fresh-address normal load
                bf8 v = *((const bf8*)(X2n + (size_t)ab * KX + 512) + tid);
#pragma unroll
                for (int j = 0; j < 8; ++j) h2s[tid * 8 + j] = b2f(v[j]);
            }
            __syncthreads();

            // phi[a] = h2 . Wphi[a] + bphi[a];  4 lanes/row, 1 pass (512 threads)
            {
                int al = tid & 3, a = tid >> 2;
                const bf8* wr = (const bf8*)(Wphib + (size_t)a * 512) + al;
                float acc = 0.f;
#pragma unroll
                for (int i = 0; i < 16; ++i) {
                    bf8 wv = wr[i * 4];
                    const float* hp2 = h2s + i * 32 + al * 8;
#pragma unroll
                    for (int j = 0; j < 8; ++j) acc += hp2[j] * b2f(wv[j]);
                }
                acc += __shfl_xor(acc, 1);
                acc += __shfl_xor(acc, 2);
                if (al == 0) phis[a] = acc + bphi[a];
            }
            __syncthreads();

            // e[t'] = phi . psi[b][t'];  4 passes (512 threads)
            {
                int al = tid & 3;
#pragma unroll
                for (int pass = 0; pass < 4; ++pass) {
                    int tt = pass * 128 + (tid >> 2);
                    const bf8* pr = (const bf8*)(psib + ((size_t)ab * TT + tt) * 128) + al;
                    float acc = 0.f;
#pragma unroll
                    for (int i = 0; i < 4; ++i) {
                        bf8 pv = pr[i * 4];
                        const float* ph = phis + i * 32 + al * 8;
#pragma unroll
                        for (int j = 0; j < 8; ++j) acc += ph[j] * b2f(pv[j]);
                    }
                    acc += __shfl_xor(acc, 1);
                    acc += __shfl_xor(acc, 2);
                    if (al == 0) es[tt] = acc;
                }
            }
            __syncthreads();

            // softmax via wave shfl reduction
            float m = es[tid];
#pragma unroll
            for (int s = 1; s < 64; s <<= 1) m = fmaxf(m, __shfl_xor(m, s));
            if (lane == 0) wred[w] = m;
            __syncthreads();
            float mx = wred[0];
#pragma unroll
            for (int i = 1; i < 8; ++i) mx = fmaxf(mx, wred[i]);
            float e0 = expf(es[tid] - mx);
            es[tid] = e0;
            float s0 = e0;
#pragma unroll
            for (int s = 1; s < 64; s <<= 1) s0 += __shfl_xor(s0, s);
            if (lane == 0) wred[8 + w] = s0;
            __syncthreads();                // also publishes es[] = exp values
            float sum = wred[8];
#pragma unroll
            for (int i = 1; i < 8; ++i) sum += wred[8 + i];
            float inv = 1.0f / sum;

            // ctx[d] from LDS-resident hT slice; 4 partials per d (512 threads)
            {
                int d = tid & 127, th = tid >> 7;
                const float* ep = es + th * 128;
                const int rb = d * 64, g0 = th * 16, sw = d & 7;
                float a0 = 0.f, a1 = 0.f, a2 = 0.f, a3 = 0.f;
#pragma unroll
                for (int i = 0; i < 16; i += 4) {
                    bf8 v0 = hTl[rb + ((g0 + i)     ^ sw)];
                    bf8 v1 = hTl[rb + ((g0 + i + 1) ^ sw)];
                    bf8 v2 = hTl[rb + ((g0 + i + 2) ^ sw)];
                    bf8 v3 = hTl[rb + ((g0 + i + 3) ^ sw)];
#pragma unroll
                    for (int j = 0; j < 8; ++j) {
                        a0 += ep[i * 8 + j]      * b2f(v0[j]);
                        a1 += ep[i * 8 + 8 + j]  * b2f(v1[j]);
                        a2 += ep[i * 8 + 16 + j] * b2f(v2[j]);
                        a3 += ep[i * 8 + 24 + j] * b2f(v3[j]);
                    }
                }
                red[tid] = (a0 + a1) + (a2 + a3);
                __syncthreads();
                float v = 0.f;
                if (th == 0)
                    v = (red[d] + red[d + 128] + red[d + 256] + red[d + 384]) * inv;
                float vp = __shfl_xor(v, 1);
                if (th == 0 && !(tid & 1)) {
                    unsigned pk = bfbits(v) | (bfbits(vp) << 16);
                    atomicExch((unsigned*)(X1n + (size_t)ab * KX + dch * 128 + d), pk); // ctx
                }
                post_flag(fC + bid * 32, (unsigned)(t + 1));
                if (th == 0)                                            // off critical path
                    scb[((size_t)ab * NS + t) * 1024 + 512 + dch * 128 + d] = __hip_bfloat16(v);
            }
        }
    }
}

// ---------------- fallback per-step kernels (plain mem ops; kernel-boundary
// coherence). Only used if cooperative launch is rejected. ----------------
__global__ __launch_bounds__(256) void fb_lstm0_kernel(
    const __hip_bfloat16* __restrict__ W1, const __hip_bfloat16* __restrict__ X1c,
    __hip_bfloat16* X1n, __hip_bfloat16* X2c, float* __restrict__ c1,
    const float* __restrict__ b1v, const float* __restrict__ woh,
    const int* __restrict__ xtok, int t)
{
    __shared__ __hip_bfloat16 Wlds[32 * 512];
    const int bid = blockIdx.x, tid = threadIdx.x;
    const int lane = tid & 63, w = tid >> 6;
    const int mr = lane & 15, quad = lane >> 4;
    {
        const bf8* src = (const bf8*)(W1 + (size_t)(bid * 16 + mr) * KX) + quad;
        bf8* dstl = (bf8*)Wlds;
        for (int ko = w; ko < 32; ko += 4) dstl[ko * 64 + lane] = src[ko * 4];
    }
    __syncthreads();
    const bf8* Wl = (const bf8*)Wlds + lane;
    const int dl = bid * 4 + quad, bb = w * 16 + mr;
    const bf8* Bq = (const bf8*)(X1c + (size_t)bb * KX) + quad;
    f4 acc = {0, 0, 0, 0};
#pragma unroll
    for (int ko = 0; ko < 32; ++ko) acc = MFMA16(Wl[ko * 64], Bq[ko * 4], acc);
    f4 bv = ((const f4*)b1v)[dl];
    f4 wo = ((const f4*)woh)[(size_t)xtok[bb * NS + t] * 512 + dl];
    acc.x += bv.x + wo.x; acc.y += bv.y + wo.y; acc.z += bv.z + wo.z; acc.w += bv.w + wo.w;
    int ci = dl * 64 + bb;
    float cn = sigm(acc.y) * c1[ci] + sigm(acc.x) * tanhf(acc.z);
    float hn = sigm(acc.w) * tanhf(cn);
    c1[ci] = cn;
    X2c[(size_t)bb * KX + dl] = __hip_bfloat16(hn);
    X1n[(size_t)bb * KX + 512 + dl] = __hip_bfloat16(hn);
}

__global__ __launch_bounds__(256) void fb_lstm1_kernel(
    const __hip_bfloat16* __restrict__ W2, const __hip_bfloat16* __restrict__ X2c,
    __hip_bfloat16* X2n, __hip_bfloat16* scb, float* __restrict__ c2,
    const float* __restrict__ b2v, int t)
{
    __shared__ __hip_bfloat16 Wlds[32 * 512];
    const int bid = blockIdx.x, tid = threadIdx.x;
    const int lane = tid & 63, w = tid >> 6;
    const int mr = lane & 15, quad = lane >> 4;
    {
        const bf8* src = (const bf8*)(W2 + (size_t)(bid * 16 + mr) * KX) + quad;
        bf8* dstl = (bf8*)Wlds;
        for (int ko = w; ko < 32; ko += 4) dstl[ko * 64 + lane] = src[ko * 4];
    }
    __syncthreads();
    const bf8* Wl = (const bf8*)Wlds + lane;
    const int dl = bid * 4 + quad, bb = w * 16 + mr;
    const bf8* Bq = (const bf8*)(X2c + (size_t)bb * KX) + quad;
    f4 acc = {0, 0, 0, 0};
#pragma unroll
    for (int ko = 0; ko < 32; ++ko) acc = MFMA16(Wl[ko * 64], Bq[ko * 4], acc);
    f4 bv = ((const f4*)b2v)[dl];
    acc.x += bv.x; acc.y += bv.y; acc.z += bv.z; acc.w += bv.w;
    int ci = dl * 64 + bb;
    float cn = sigm(acc.y) * c2[ci] + sigm(acc.x) * tanhf(acc.z);
    float hn = sigm(acc.w) * tanhf(cn);
    c2[ci] = cn;
    X2n[(size_t)bb * KX + 512 + dl] = __hip_bfloat16(hn);
    scb[((size_t)bb * NS + t) * 1024 + dl] = __hip_bfloat16(hn);
}

__global__ __launch_bounds__(256) void fb_attn_kernel(
    const __hip_bfloat16* __restrict__ X2n, const __hip_bfloat16* __restrict__ Wphib,
    const float* __restrict__ bphi, const __hip_bfloat16* __restrict__ psib,
    const __hip_bfloat16* __restrict__ hT,
    __hip_bfloat16* X1n, __hip_bfloat16* scb, int t)
{
    __shared__ float h2s[512], phis[128], es[512], red[256];
    int b = blockIdx.x >> 2, dch = blockIdx.x & 3;
    int tid = threadIdx.x;
    if (tid < 64) {
        bf8 v = *((const bf8*)(X2n + (size_t)b * KX + 512) + tid);
#pragma unroll
        for (int j = 0; j < 8; ++j) h2s[tid * 8 + j] = b2f(v[j]);
    }
    __syncthreads();
    {
        int al = tid & 3;
#pragma unroll
        for (int pass = 0; pass < 2; ++pass) {
            int a = pass * 64 + (tid >> 2);
            const bf8* wr = (const bf8*)(Wphib + (size_t)a * 512) + al;
            float acc = 0.f;
#pragma unroll
            for (int i = 0; i < 16; ++i) {
                bf8 wv = wr[i * 4];
                const float* hp2 = h2s + i * 32 + al * 8;
#pragma unroll
                for (int j = 0; j < 8; ++j) acc += hp2[j] * b2f(wv[j]);
            }
            acc += __shfl_xor(acc, 1);
            acc += __shfl_xor(acc, 2);
            if (al == 0) phis[a] = acc + bphi[a];
        }
    }
    __syncthreads();
    {
        int al = tid & 3;
#pragma unroll
        for (int pass = 0; pass < 8; ++pass) {
            int tt = pass * 64 + (tid >> 2);
            const bf8* pr = (const bf8*)(psib + ((size_t)b * TT + tt) * 128) + al;
            float acc = 0.f;
#pragma unroll
            for (int i = 0; i < 4; ++i) {
                bf8 pv = pr[i * 4];
                const float* ph = phis + i * 32 + al * 8;
#pragma unroll
                for (int j = 0; j < 8; ++j) acc += ph[j] * b2f(pv[j]);
            }
            acc += __shfl_xor(acc, 1);
            acc += __shfl_xor(acc, 2);
            if (al == 0) es[tt] = acc;
        }
    }
    __syncthreads();
    red[tid] = fmaxf(es[tid], es[tid + 256]);
    __syncthreads();
    for (int st = 128; st > 0; st >>= 1) {
        if (tid < st) red[tid] = fmaxf(red[tid], red[tid + st]);
        __syncthreads();
    }
    float mx = red[0];
    __syncthreads();
    float e0 = expf(es[tid] - mx), e1 = expf(es[tid + 256] - mx);
    es[tid] = e0; es[tid + 256] = e1;
    red[tid] = e0 + e1;
    __syncthreads();
    for (int st = 128; st > 0; st >>= 1) {
        if (tid < st) red[tid] += red[tid + st];
        __syncthreads();
    }
    float inv = 1.0f / red[0];
    __syncthreads();
    {
        int d = dch * 128 + (tid & 127), th = tid >> 7;
        const bf8* hp = (const bf8*)hT + ((size_t)b * SD + d) * 64 + th * 32;
        const float* ep = es + th * 256;
        float a0 = 0.f, a1 = 0.f, a2 = 0.f, a3 = 0.f;
#pragma unroll
        for (int i = 0; i < 32; i += 4) {
            bf8 v0 = hp[i], v1 = hp[i + 1], v2 = hp[i + 2], v3 = hp[i + 3];
#pragma unroll
            for (int j = 0; j < 8; ++j) {
                a0 += ep[i * 8 + j]      * b2f(v0[j]);
                a1 += ep[i * 8 + 8 + j]  * b2f(v1[j]);
                a2 += ep[i * 8 + 16 + j] * b2f(v2[j]);
                a3 += ep[i * 8 + 24 + j] * b2f(v3[j]);
            }
        }
        float acc = (a0 + a1) + (a2 + a3);
        red[tid] = acc;
        __syncthreads();
        if (th == 0) {
            float v = (acc + red[tid + 128]) * inv;
            X1n[(size_t)b * KX + d] = __hip_bfloat16(v);
            scb[((size_t)b * NS + t) * 1024 + 512 + d] = __hip_bfloat16(v);
        }
    }
}

// ---------------- psi GEMM: psibf[b*512+t][128] = hbf @ Wpsi^T + bpsi ----------------
__global__ __launch_bounds__(256) void psi_gemm_kernel(
    const __hip_bfloat16* __restrict__ A,   // hbf [32768][512]
    const __hip_bfloat16* __restrict__ Bw,  // Wpsibf [128][512]
    const float* __restrict__ bias,
    __hip_bfloat16* __restrict__ C)         // [32768][128]
{
    int lane = threadIdx.x & 63, wave = threadIdx.x >> 6;
    int m0 = (blockIdx.x * 4 + wave) * 16;
    int mr = lane & 15, quad = lane >> 4;
    const bf8* Ar = (const bf8*)(A + (size_t)(m0 + mr) * 512 + quad * 8);
    f4 acc[8] = {};
    for (int k0 = 0; k0 < 512; k0 += 32) {
        int ko = k0 >> 3;
        bf8 a = Ar[ko];
#pragma unroll
        for (int nf = 0; nf < 8; ++nf) {
            const bf8* Br = (const bf8*)(Bw + (size_t)(nf * 16 + mr) * 512 + quad * 8);
            acc[nf] = MFMA16(a, Br[ko], acc[nf]);
        }
    }
#pragma unroll
    for (int nf = 0; nf < 8; ++nf) {
        int n = nf * 16 + mr;
        float bs = bias[n];
#pragma unroll
        for (int r = 0; r < 4; ++r) {
            int m = m0 + quad * 4 + r;
            C[(size_t)m * 128 + n] = __hip_bfloat16(acc[nf][r] + bs);
        }
    }
}

// ---------------- final projection: out[b*128+t][64] = scbf @ Wcd^T + bcd ----------------
__global__ __launch_bounds__(256) void out_gemm_kernel(
    const __hip_bfloat16* __restrict__ A,   // scbf [8192][1024]
    const __hip_bfloat16* __restrict__ Bw,  // Wcdbf [64][1024]
    const float* __restrict__ bias,
    float* __restrict__ C)                  // [8192][64]
{
    int lane = threadIdx.x & 63, wave = threadIdx.x >> 6;
    int m0 = (blockIdx.x * 4 + wave) * 16;
    int mr = lane & 15, quad = lane >> 4;
    const bf8* Ar = (const bf8*)(A + (size_t)(m0 + mr) * 1024 + quad * 8);
    f4 acc[4] = {};
    for (int k0 = 0; k0 < 1024; k0 += 32) {
        int ko = k0 >> 3;
        bf8 a = Ar[ko];
#pragma unroll
        for (int nf = 0; nf < 4; ++nf) {
            const bf8* Br = (const bf8*)(Bw + (size_t)(nf * 16 + mr) * 1024 + quad * 8);
            acc[nf] = MFMA16(a, Br[ko], acc[nf]);
        }
    }
#pragma unroll
    for (int nf = 0; nf < 4; ++nf) {
        int n = nf * 16 + mr;
        float bs = bias[n];
#pragma unroll
        for (int r = 0; r < 4; ++r) {
            int m = m0 + quad * 4 + r;
            C[(size_t)m * 64 + n] = acc[nf][r] + bs;
        }
    }
}

extern "C" void kernel_launch(void* const* d_in, const int* in_sizes, int n_in,
                              void* d_out, int out_size, void* d_ws, size_t ws_size,
                              hipStream_t stream)
{
    const int*   x    = (const int*)  d_in[0];
    const float* h    = (const float*)d_in[1];
    const float* Wih0 = (const float*)d_in[2];
    const float* Whh0 = (const float*)d_in[3];
    const float* bih0 = (const float*)d_in[4];
    const float* bhh0 = (const float*)d_in[5];
    const float* Wih1 = (const float*)d_in[6];
    const float* Whh1 = (const float*)d_in[7];
    const float* bih1 = (const float*)d_in[8];
    const float* bhh1 = (const float*)d_in[9];
    const float* Wphi = (const float*)d_in[10];
    const float* bphi = (const float*)d_in[11];
    const float* Wpsi = (const float*)d_in[12];
    const float* bpsi = (const float*)d_in[13];
    const float* Wcd  = (const float*)d_in[14];
    const float* bcd  = (const float*)d_in[15];
    float* out = (float*)d_out;

    char* p = (char*)d_ws;
    __hip_bfloat16* hbf    = (__hip_bfloat16*)p; p += (size_t)BB * TT * SD * 2;   // 32 MB (hbf, then hT)
    __hip_bfloat16* psibf  = (__hip_bfloat16*)p; p += (size_t)BB * TT * ATT * 2;  // 8 MB
    __hip_bfloat16* scbf   = (__hip_bfloat16*)p; p += (size_t)BB * NS * 1024 * 2; // 16 MB
    __hip_bfloat16* W1aug  = (__hip_bfloat16*)p; p += (size_t)2048 * KX * 2;      // 4 MB
    __hip_bfloat16* W2aug  = (__hip_bfloat16*)p; p += (size_t)2048 * KX * 2;      // 4 MB
    __hip_bfloat16* Wphib  = (__hip_bfloat16*)p; p += (size_t)ATT * SD * 2;
    __hip_bfloat16* Wpsib  = (__hip_bfloat16*)p; p += (size_t)ATT * SD * 2;
    __hip_bfloat16* Wcdb   = (__hip_bfloat16*)p; p += (size_t)NC * 1024 * 2;
    // per-step X buffers: fresh addresses each step => L2-cacheable reads
    __hip_bfloat16* X1base = (__hip_bfloat16*)p; p += (size_t)(NS + 1) * BB * KX * 2;  // 16.5 MB
    __hip_bfloat16* X2base = (__hip_bfloat16*)p; p += (size_t)(NS + 1) * BB * KX * 2;  // 16.5 MB
    float* b1v = (float*)p; p += 512 * 4 * 4;
    float* b2v = (float*)p; p += 512 * 4 * 4;
    float* woh = (float*)p; p += (size_t)64 * 512 * 4 * 4;   // 512 KB
    float* c1  = (float*)p; p += (size_t)SD * BB * 4;
    float* c2  = (float*)p; p += (size_t)SD * BB * 4;
    unsigned* bar = (unsigned*)p; p += 16384 * 4;            // fA/fB/fC flag lines

    // ---- one-time prep ----
    f2b_kernel<<<16384, 256, 0, stream>>>(h, hbf, BB * TT * SD);
    f2b_kernel<<<64, 256, 0, stream>>>(Wphi, Wphib, ATT * SD);
    f2b_kernel<<<64, 256, 0, stream>>>(Wpsi, Wpsib, ATT * SD);
    f2b_kernel<<<64, 256, 0, stream>>>(Wcd, Wcdb, NC * 1024);
    prep_w1_kernel<<<(2048 * KX + 255) / 256, 256, 0, stream>>>(Wih0, Whh0, W1aug);
    prep_w2_kernel<<<(2048 * KX + 255) / 256, 256, 0, stream>>>(Wih1, Whh1, W2aug);
    prep_misc_kernel<<<(64 * 512 + 255) / 256, 256, 0, stream>>>(Wih0, bih0, bhh0, bih1, bhh1,
                                                                 b1v, b2v, woh);
    init_kernel<<<(64 * KX + 255) / 256, 256, 0, stream>>>(h, X1base, X2base, c1, c2, bar);
    psi_gemm_kernel<<<512, 256, 0, stream>>>(hbf, Wpsib, bpsi, psibf);
    transpose_h_kernel<<<4096, 256, 0, stream>>>(h, hbf);   // overwrite hbf with hT [b][d][t]
    __hip_bfloat16* hT = hbf;

    // ---- persistent decode ----
    const __hip_bfloat16 *a0 = W1aug, *a1 = W2aug, *a2 = Wphib;
    const float* a3 = bphi;
    const __hip_bfloat16 *a4 = psibf, *a5 = hT;
    __hip_bfloat16 *a6 = X1base, *a7 = X2base, *a8 = scbf;
    const int* a9 = x;
    const float *a10 = b1v, *a11 = b2v, *a12 = woh;
    unsigned* a13 = bar;
    void* args[14] = {&a0, &a1, &a2, &a3, &a4, &a5, &a6, &a7,
                      &a8, &a9, &a10, &a11, &a12, &a13};
    hipError_t ce = hipLaunchCooperativeKernel((const void*)decode_kernel,
                                               dim3(256), dim3(512), args, 0, stream);
    if (ce != hipSuccess) {
        (void)hipGetLastError();
        for (int t = 0; t < NS; ++t) {
            __hip_bfloat16* X1c = X1base + (size_t)t * BB * KX;
            __hip_bfloat16* X1n = X1c + (size_t)BB * KX;
            __hip_bfloat16* X2c = X2base + (size_t)t * BB * KX;
            __hip_bfloat16* X2n = X2c + (size_t)BB * KX;
            fb_lstm0_kernel<<<128, 256, 0, stream>>>(W1aug, X1c, X1n, X2c, c1, b1v, woh, x, t);
            fb_lstm1_kernel<<<128, 256, 0, stream>>>(W2aug, X2c, X2n, scbf, c2, b2v, t);
            fb_attn_kernel<<<256, 256, 0, stream>>>(X2n, Wphib, bphi, psibf, hT, X1n, scbf, t);
        }
    }
    // output projection
    out_gemm_kernel<<<128, 256, 0, stream>>>(scbf, Wcdb, bcd, out);
}